// Round 12
// baseline (257.510 us; speedup 1.0000x reference)
//
#include <hip/hip_runtime.h>
#include <hip/hip_fp16.h>

#define IRR    56
#define EF     48
#define WN     832
#define NEDGE  160000
#define NNODE  8000
#define NT     256
#define EBK    64                  // edges per block
#define GRID   ((NEDGE / EBK) * 4) // 2500 tasks x 4 flavors

#define INV_SQRT3 0.5773502691896258f
#define INV_SQRT2 0.7071067811865476f
#define A_SCAL    0.22360679774997896f   // 1/sqrt(20)
#define A_VEC     0.20412414523193154f   // 1/sqrt(24)

typedef __bf16 bf16x8 __attribute__((ext_vector_type(8)));
typedef float  f32x4  __attribute__((ext_vector_type(4)));
typedef unsigned short u16x8 __attribute__((ext_vector_type(8)));
typedef unsigned short u16x4 __attribute__((ext_vector_type(4)));

__device__ __forceinline__ unsigned short f2bf(float f) {
    unsigned int u = __builtin_bit_cast(unsigned int, f);
    u += 0x7FFFu + ((u >> 16) & 1u);          // RNE
    return (unsigned short)(u >> 16);
}
__device__ __forceinline__ unsigned short f2h(float f) {
    __half h = __float2half(f);
    return __builtin_bit_cast(unsigned short, h);
}
__device__ __forceinline__ float h2f(unsigned short u) {
    __half h = __builtin_bit_cast(__half, u);
    return __half2float(h);
}

// ---- setup: W1T [n][64] + W2L lane-major fragments + edge_attr->bf16 + src hist ----
// W2L[o]: o = ((i*2+f)*64 + l)*8 + j ; lane l=(q*16+m); value = W2[k=f*32+q*8+j][n=i*16+m]
__global__ void k_setup(const float* __restrict__ w1, const float* __restrict__ b1,
                        const float* __restrict__ w2, const float* __restrict__ b2,
                        const float* __restrict__ edge_attr, const int* __restrict__ edge_index,
                        unsigned short* __restrict__ W1T, unsigned short* __restrict__ W2L,
                        unsigned short* __restrict__ EAB, int* __restrict__ hist)
{
    size_t o = (size_t)blockIdx.x * 256 + threadIdx.x;
    if (o < (size_t)NEDGE * EF) EAB[o] = f2bf(edge_attr[o]);   // row-major [e][k]
    if (o < 52 * 2 * 64 * 8) {
        int i = (int)(o >> 10);
        int rem = (int)(o & 1023);
        int f = rem >> 9;
        int rem2 = rem & 511;
        int l = rem2 >> 3, j = rem2 & 7;
        int mm = l & 15, qq = l >> 4;
        int k = f * 32 + qq * 8 + j;
        int n = i * 16 + mm;
        float v = (k < EF) ? w2[k * WN + n] : ((k == EF) ? b2[n] : 0.f);
        W2L[o] = f2bf(v);
    }
    if (o < EF * EF) { int k = (int)o / EF, n = (int)o - k * EF; W1T[n * 64 + k] = f2bf(w1[o]); }
    if (o < EF * 16) { int n = (int)o >> 4, kk = EF + ((int)o & 15); W1T[n * 64 + kk] = (kk == EF) ? f2bf(b1[n]) : (unsigned short)0; }
    if (o < NEDGE) atomicAdd(&hist[edge_index[o]], 1);
}

__global__ __launch_bounds__(NT, 3) void tp_fused(
    const float* __restrict__ node_attr,
    const float* __restrict__ edge_sh,
    const int*   __restrict__ edge_index,
    const int*   __restrict__ hist,
    const unsigned short* __restrict__ W1T,
    const unsigned short* __restrict__ W2L,
    const unsigned short* __restrict__ EAB,
    float* __restrict__ out)
{
    __shared__ __align__(16) unsigned short sW2[13 * 1024];     // 26624 B resident W2 quarter
    __shared__ __align__(16) unsigned char  UGH[EBK * 56 * 4];  // 14336 B: sG f32(56) -> sH u16(72) overlay
    __shared__ __align__(16) unsigned short sF[EBK * 64];       // 8192 B: sO overlays (stride 32 f32 == 64 u16)
    __shared__ float sS1[EBK][4];
    __shared__ int   sSrc[EBK], sDst[EBK];
    __shared__ float sInv[EBK];

    float*          sG = (float*)UGH;            // stride 56 f32
    unsigned short* sH = (unsigned short*)UGH;   // stride 72 u16
    float*          sO = (float*)sF;             // stride 32 f32 (rows == sF rows -> wave-private)

    const int tid    = threadIdx.x;
    const int lane   = tid & 63;
    const int wv     = tid >> 6;
    const int m      = lane & 15;
    const int quad   = lane >> 4;
    const int flavor = blockIdx.x & 3;           // tiles flavor*13 .. flavor*13+12
    const int e0     = (blockIdx.x >> 2) * EBK;
    const int em     = wv * 16 + m;              // block-local edge owned by lane

    // ---- P0: indices ----
    if (tid < EBK)           sSrc[tid]       = edge_index[e0 + tid];
    else if (tid < 2 * EBK)  sDst[tid - EBK] = edge_index[NEDGE + e0 + tid - EBK];
    __syncthreads();

    // ---- P1: stage W2 quarter + flavor-trimmed gather + sInv ----
    {
        const uint4* src = (const uint4*)(W2L + (size_t)flavor * 13 * 1024);
        uint4* dst = (uint4*)sW2;
        #pragma unroll
        for (int it = 0; it < 7; it++) {
            int idx = it * NT + tid;
            if (idx < 1664) dst[idx] = src[idx];
        }
    }
    if (flavor == 0 || flavor == 3) {
        int e = tid >> 2, c = tid & 3;
        int off = (flavor == 0) ? 0 : 40;        // f0 needs x[0..15], f3 needs x[40..55]
        *(float4*)&sG[e * 56 + off + c * 4] =
            *(const float4*)&node_attr[(size_t)sDst[e] * IRR + off + c * 4];
    } else {
        int off = (flavor == 1) ? 0 : 16;        // f1: x[0..39], f2: x[16..55]
        #pragma unroll
        for (int it = 0; it < 3; it++) {
            int idx = it * NT + tid;
            if (idx < 640) {
                int e = idx / 10, c = idx - e * 10;
                *(float4*)&sG[e * 56 + off + c * 4] =
                    *(const float4*)&node_attr[(size_t)sDst[e] * IRR + off + c * 4];
            }
        }
    }
    if (tid >= 192) {
        int e = tid - 192;
        sInv[e] = 1.0f / fmaxf((float)hist[sSrc[e]], 1.0f);
    }
    __syncthreads();

    // ---- P2: F features (quad0 lanes; flavor-specific subset), fp16 ----
    if (quad == 0) {
        const float* x = sG + em * 56;
        float4 sh4 = *(const float4*)&edge_sh[(size_t)(e0 + em) * 4];
        const float s0 = sh4.x, sx = sh4.y, sy = sh4.z, sz = sh4.w;
        unsigned short* F = sF + em * 64;
        const float c0S = s0 * A_SCAL;
        const float c0V = s0 * A_VEC;
        const float cD3 = INV_SQRT3 * A_SCAL;
        const float cC2 = INV_SQRT2 * A_VEC;
        if (flavor == 0) {
            #pragma unroll
            for (int u = 0; u < 13; u++) F[u] = f2h(x[u] * c0S);           // wA0[0..12]
        } else if (flavor == 1) {
            #pragma unroll
            for (int u = 13; u < 16; u++) F[u] = f2h(x[u] * c0S);          // wA0[13..15]
            #pragma unroll
            for (int u = 0; u < 16; u++) F[20 + u] = f2h(x[u] * A_VEC);    // wA1
            #pragma unroll
            for (int u = 0; u < 4; u++) {
                float a0 = x[16+u*3], a1 = x[17+u*3], a2 = x[18+u*3];      // x1o
                float b0 = x[28+u*3], b1 = x[29+u*3], b2 = x[30+u*3];      // x1e
                F[16 + u] = f2h((a0*sx + a1*sy + a2*sz) * cD3);            // wB0 dot_b
                F[36+u*3+0] = f2h(a0 * c0V);                               // wB1
                F[36+u*3+1] = f2h(a1 * c0V);
                F[36+u*3+2] = f2h(a2 * c0V);
                F[48+u*3+0] = f2h((b1*sz - b2*sy) * cC2);                  // wC1 cross(x1e,s1)
                F[48+u*3+1] = f2h((b2*sx - b0*sz) * cC2);
                F[48+u*3+2] = f2h((b0*sy - b1*sx) * cC2);
            }
            sS1[em][0] = sx; sS1[em][1] = sy; sS1[em][2] = sz;
        } else if (flavor == 2) {
            #pragma unroll
            for (int u = 0; u < 4; u++) {
                float a0 = x[16+u*3], a1 = x[17+u*3], a2 = x[18+u*3];      // x1o
                float b0 = x[28+u*3], b1 = x[29+u*3], b2 = x[30+u*3];      // x1e
                F[u*3+0] = f2h((a1*sz - a2*sy) * cC2);                     // wB1e cross(x1o,s1)
                F[u*3+1] = f2h((a2*sx - a0*sz) * cC2);
                F[u*3+2] = f2h((a0*sy - a1*sx) * cC2);
                F[12+u*3+0] = f2h(b0 * c0V);                               // wC1e
                F[12+u*3+1] = f2h(b1 * c0V);
                F[12+u*3+2] = f2h(b2 * c0V);
                F[40 + u] = f2h((b0*sx + b1*sy + b2*sz) * cD3);            // wC0o dot_c
            }
            #pragma unroll
            for (int u = 0; u < 16; u++) F[24 + u] = f2h(x[40+u] * A_VEC); // wD1e
            #pragma unroll
            for (int u = 0; u < 3; u++)  F[44 + u] = f2h(x[40+u] * c0S);   // wD0o[0..2]
            sS1[em][0] = sx; sS1[em][1] = sy; sS1[em][2] = sz;
        } else {
            #pragma unroll
            for (int u = 3; u < 16; u++) F[44 + u] = f2h(x[40+u] * c0S);   // wD0o[3..15]
        }
    }
    __syncthreads();   // sG reads done; sH may overlay

    // ---- P3: GEMM1 transposed (bf16 edge_attr table): lane holds H[e=em][hid] ----
    {
        const unsigned short* ea = EAB + (size_t)(e0 + em) * EF;
        u16x8 ub0 = *(const u16x8*)(ea + quad * 8);
        u16x8 ub1 = {0,0,0,0,0,0,0,0};
        if (quad < 2)       ub1 = *(const u16x8*)(ea + 32 + quad * 8);
        else if (quad == 2) ub1[0] = 0x3F80;     // bias row k=48 -> 1.0
        bf16x8 hb0 = __builtin_bit_cast(bf16x8, ub0);
        bf16x8 hb1 = __builtin_bit_cast(bf16x8, ub1);

        #pragma unroll
        for (int nth = 0; nth < 3; nth++) {
            bf16x8 a0 = __builtin_bit_cast(bf16x8, *(const u16x8*)&W1T[(nth*16 + m)*64 + quad*8]);
            bf16x8 a1 = __builtin_bit_cast(bf16x8, *(const u16x8*)&W1T[(nth*16 + m)*64 + 32 + quad*8]);
            f32x4 c = {0.f, 0.f, 0.f, 0.f};
            c = __builtin_amdgcn_mfma_f32_16x16x32_bf16(a0, hb0, c, 0, 0, 0);
            c = __builtin_amdgcn_mfma_f32_16x16x32_bf16(a1, hb1, c, 0, 0, 0);
            u16x4 hp;
            #pragma unroll
            for (int r = 0; r < 4; r++) hp[r] = f2bf(fmaxf(c[r], 0.f));
            *(u16x4*)&sH[em * 72 + nth*16 + quad*4] = hp;
        }
        if (quad == 3) {
            u16x4 b = {0x3F80, 0, 0, 0}, z = {0, 0, 0, 0};
            *(u16x4*)&sH[em * 72 + 48] = b;
            *(u16x4*)&sH[em * 72 + 52] = z;
            *(u16x4*)&sH[em * 72 + 56] = z;
            *(u16x4*)&sH[em * 72 + 60] = z;
        }
    }
    __syncthreads();

    // ---- P4: consume 13 tiles (flavor-specific); sF/sO rows wave-private ----
    bf16x8 HB0 = __builtin_bit_cast(bf16x8, *(const u16x8*)&sH[em * 72 + quad*8]);
    bf16x8 HB1 = __builtin_bit_cast(bf16x8, *(const u16x8*)&sH[em * 72 + 32 + quad*8]);
    const unsigned short* Fp = sF + em * 64;

    if (flavor == 0) {
        float oe[4] = {0.f,0.f,0.f,0.f};
        #pragma unroll
        for (int i = 0; i < 13; i++) {
            u16x8 Af = *(const u16x8*)&sW2[i * 1024 + lane * 8];
            u16x8 Bf = *(const u16x8*)&sW2[i * 1024 + 512 + lane * 8];
            f32x4 c = {0.f,0.f,0.f,0.f};
            c = __builtin_amdgcn_mfma_f32_16x16x32_bf16(__builtin_bit_cast(bf16x8, Af), HB0, c, 0, 0, 0);
            c = __builtin_amdgcn_mfma_f32_16x16x32_bf16(__builtin_bit_cast(bf16x8, Bf), HB1, c, 0, 0, 0);
            float f = h2f(Fp[i]);
            #pragma unroll
            for (int r = 0; r < 4; r++) oe[r] += f * c[r];
        }
        float4 v; v.x = oe[0]; v.y = oe[1]; v.z = oe[2]; v.w = oe[3];
        *(float4*)&sO[em * 32 + quad*4] = v;                       // ch 0..15 partial
    } else if (flavor == 1) {
        float oe[4] = {0.f,0.f,0.f,0.f};
        float sA[4] = {0.f,0.f,0.f,0.f};
        float t1[12] = {0.f,0.f,0.f,0.f,0.f,0.f,0.f,0.f,0.f,0.f,0.f,0.f};
        #pragma unroll
        for (int i = 0; i < 13; i++) {
            u16x8 Af = *(const u16x8*)&sW2[i * 1024 + lane * 8];
            u16x8 Bf = *(const u16x8*)&sW2[i * 1024 + 512 + lane * 8];
            f32x4 c = {0.f,0.f,0.f,0.f};
            c = __builtin_amdgcn_mfma_f32_16x16x32_bf16(__builtin_bit_cast(bf16x8, Af), HB0, c, 0, 0, 0);
            c = __builtin_amdgcn_mfma_f32_16x16x32_bf16(__builtin_bit_cast(bf16x8, Bf), HB1, c, 0, 0, 0);
            if (i < 7) {
                float f = h2f(Fp[13 + i]);
                #pragma unroll
                for (int r = 0; r < 4; r++) oe[r] += f * c[r];
            } else if (i < 11) {
                float f = h2f(Fp[20 + (i - 7)*4 + quad]);
                #pragma unroll
                for (int r = 0; r < 4; r++) sA[r] += f * c[r];
            } else {
                int u = (i - 11)*4 + quad;
                #pragma unroll
                for (int i3 = 0; i3 < 3; i3++) {
                    float f = h2f(Fp[36 + u*3 + i3]);
                    #pragma unroll
                    for (int r = 0; r < 4; r++) t1[i3*4 + r] += f * c[r];
                }
            }
        }
        #pragma unroll
        for (int r = 0; r < 4; r++) {
            sA[r] += __shfl_xor(sA[r], 16, 64);  sA[r] += __shfl_xor(sA[r], 32, 64);
        }
        #pragma unroll
        for (int i = 0; i < 12; i++) {
            t1[i] += __shfl_xor(t1[i], 16, 64);  t1[i] += __shfl_xor(t1[i], 32, 64);
        }
        float4 v; v.x = oe[0]; v.y = oe[1]; v.z = oe[2]; v.w = oe[3];
        *(float4*)&sO[em * 32 + quad*4] = v;                       // ch 0..15 partial
        if (quad == 0) {
            float s1x = sS1[em][0], s1y = sS1[em][1], s1z = sS1[em][2];
            #pragma unroll
            for (int r = 0; r < 4; r++) {                          // ch 16..27 (o1o)
                sO[em * 32 + 16 + r*3 + 0] = sA[r] * s1x + t1[0*4 + r];
                sO[em * 32 + 16 + r*3 + 1] = sA[r] * s1y + t1[1*4 + r];
                sO[em * 32 + 16 + r*3 + 2] = sA[r] * s1z + t1[2*4 + r];
            }
        }
    } else if (flavor == 2) {
        float sD[4] = {0.f,0.f,0.f,0.f};
        float t1[12] = {0.f,0.f,0.f,0.f,0.f,0.f,0.f,0.f,0.f,0.f,0.f,0.f};
        float oo[4] = {0.f,0.f,0.f,0.f};
        #pragma unroll
        for (int i = 0; i < 13; i++) {
            u16x8 Af = *(const u16x8*)&sW2[i * 1024 + lane * 8];
            u16x8 Bf = *(const u16x8*)&sW2[i * 1024 + 512 + lane * 8];
            f32x4 c = {0.f,0.f,0.f,0.f};
            c = __builtin_amdgcn_mfma_f32_16x16x32_bf16(__builtin_bit_cast(bf16x8, Af), HB0, c, 0, 0, 0);
            c = __builtin_amdgcn_mfma_f32_16x16x32_bf16(__builtin_bit_cast(bf16x8, Bf), HB1, c, 0, 0, 0);
            if (i < 2) {
                int j = i*4 + quad;
                #pragma unroll
                for (int i3 = 0; i3 < 3; i3++) {
                    float f = h2f(Fp[j*3 + i3]);
                    #pragma unroll
                    for (int r = 0; r < 4; r++) t1[i3*4 + r] += f * c[r];
                }
            } else if (i < 6) {
                float f = h2f(Fp[24 + (i - 2)*4 + quad]);
                #pragma unroll
                for (int r = 0; r < 4; r++) sD[r] += f * c[r];
            } else {
                float f = h2f(Fp[40 + (i - 6)]);
                #pragma unroll
                for (int r = 0; r < 4; r++) oo[r] += f * c[r];
            }
        }
        #pragma unroll
        for (int r = 0; r < 4; r++) {
            sD[r] += __shfl_xor(sD[r], 16, 64);  sD[r] += __shfl_xor(sD[r], 32, 64);
        }
        #pragma unroll
        for (int i = 0; i < 12; i++) {
            t1[i] += __shfl_xor(t1[i], 16, 64);  t1[i] += __shfl_xor(t1[i], 32, 64);
        }
        float4 v; v.x = oo[0]; v.y = oo[1]; v.z = oo[2]; v.w = oo[3];
        *(float4*)&sO[em * 32 + 12 + quad*4] = v;                  // local 12..27 -> ch 40..55 partial
        if (quad == 0) {
            float s1x = sS1[em][0], s1y = sS1[em][1], s1z = sS1[em][2];
            #pragma unroll
            for (int r = 0; r < 4; r++) {                          // local 0..11 -> ch 28..39 (o1e)
                sO[em * 32 + r*3 + 0] = sD[r] * s1x + t1[0*4 + r];
                sO[em * 32 + r*3 + 1] = sD[r] * s1y + t1[1*4 + r];
                sO[em * 32 + r*3 + 2] = sD[r] * s1z + t1[2*4 + r];
            }
        }
    } else {
        float oo[4] = {0.f,0.f,0.f,0.f};
        #pragma unroll
        for (int i = 0; i < 13; i++) {
            u16x8 Af = *(const u16x8*)&sW2[i * 1024 + lane * 8];
            u16x8 Bf = *(const u16x8*)&sW2[i * 1024 + 512 + lane * 8];
            f32x4 c = {0.f,0.f,0.f,0.f};
            c = __builtin_amdgcn_mfma_f32_16x16x32_bf16(__builtin_bit_cast(bf16x8, Af), HB0, c, 0, 0, 0);
            c = __builtin_amdgcn_mfma_f32_16x16x32_bf16(__builtin_bit_cast(bf16x8, Bf), HB1, c, 0, 0, 0);
            float f = h2f(Fp[47 + i]);
            #pragma unroll
            for (int r = 0; r < 4; r++) oo[r] += f * c[r];
        }
        float4 v; v.x = oo[0]; v.y = oo[1]; v.z = oo[2]; v.w = oo[3];
        *(float4*)&sO[em * 32 + quad*4] = v;                       // local 0..15 -> ch 40..55 partial
    }
    __syncthreads();

    // ---- P5: pre-scaled channel-major atomic scatter into d_out ----
    if (flavor == 1 || flavor == 2) {
        const int chBase = (flavor == 1) ? 0 : 28;
        #pragma unroll
        for (int it = 0; it < 7; it++) {
            int idx = it * NT + tid;           // 1792 = 64*28
            int e = idx / 28, ch = idx - e * 28;
            unsafeAtomicAdd(&out[(size_t)sSrc[e] * IRR + chBase + ch], sO[e * 32 + ch] * sInv[e]);
        }
    } else {
        const int chBase = (flavor == 0) ? 0 : 40;
        #pragma unroll
        for (int it = 0; it < 4; it++) {
            int idx = it * NT + tid;           // 1024 = 64*16
            int e = idx >> 4, ch = idx & 15;
            unsafeAtomicAdd(&out[(size_t)sSrc[e] * IRR + chBase + ch], sO[e * 32 + ch] * sInv[e]);
        }
    }
}

extern "C" void kernel_launch(void* const* d_in, const int* in_sizes, int n_in,
                              void* d_out, int out_size, void* d_ws, size_t ws_size,
                              hipStream_t stream) {
    const float* node_attr  = (const float*)d_in[0];
    const float* edge_attr  = (const float*)d_in[1];
    const float* edge_sh    = (const float*)d_in[2];
    const float* fc_w1      = (const float*)d_in[3];
    const float* fc_b1      = (const float*)d_in[4];
    const float* fc_w2      = (const float*)d_in[5];
    const float* fc_b2      = (const float*)d_in[6];
    const int*   edge_index = (const int*)d_in[7];

    int* hist = (int*)d_ws;                                    // 8000 ints
    unsigned short* W1T = (unsigned short*)(hist + NNODE);     // 48*64 = 3072 u16
    unsigned short* W2L = W1T + EF * 64;                       // 53248 u16
    unsigned short* EAB = W2L + 52 * 2 * 64 * 8;               // 160000*48 u16

    hipMemsetAsync(hist, 0, NNODE * sizeof(int), stream);
    hipMemsetAsync(d_out, 0, (size_t)out_size * sizeof(float), stream);

    k_setup<<<(NEDGE * EF + 255) / 256, 256, 0, stream>>>(
        fc_w1, fc_b1, fc_w2, fc_b2, edge_attr, edge_index, W1T, W2L, EAB, hist);

    tp_fused<<<GRID, NT, 0, stream>>>(node_attr, edge_sh, edge_index, hist,
                                      W1T, W2L, EAB, (float*)d_out);
}